// Round 6
// baseline (277.454 us; speedup 1.0000x reference)
//
#include <hip/hip_runtime.h>
#include <hip/hip_bf16.h>

// HyperbolicContrastiveLoss: N=8192, D=512, f32 in, scalar f32 out.
// loss = (1/2N) * sum_i [ log(sum_j exp(sim_ij)) + log(sum_i exp(sim_ij)) - 2*sim_ii ]
// exp(sim) = exp(-arccosh(arg)) = arg - sqrt(arg^2-1)  (exact; (arg+s)(arg-s)=1)
// GEMM: 256x256 tile, 8 waves (2M x 4N), BK=64, double-buffered global_load_lds
// with XOR-swizzled LDS (pre-swizzled global source + same XOR on reads).

#define NROWS 8192
#define DDIM  512
#define BM 256
#define BN 256
#define BK 64
#define NT (DDIM / BK)       // 8 K-steps
#define LDSBUF 65536         // per-buffer bytes: A 32K | B 32K

typedef __attribute__((ext_vector_type(8))) short bf16x8;
typedef __attribute__((ext_vector_type(4))) float f32x4;

constexpr float EPSF = 1e-10f;

#define GLOAD_LDS16(g, l)                                                        \
    __builtin_amdgcn_global_load_lds(                                            \
        (const __attribute__((address_space(1))) void*)(g),                      \
        (__attribute__((address_space(3))) void*)(l), 16, 0, 0)

__device__ inline unsigned short f2bf(float f) {
    union { float f; unsigned int u; } x; x.f = f;
    unsigned int r = x.u + 0x7fffu + ((x.u >> 16) & 1u);  // RNE
    return (unsigned short)(r >> 16);
}

// One wave per row: convert audio+text row to bf16, row norms, and f32-precise
// diagonal sim_ii.
__global__ __launch_bounds__(256) void convert_norms(const float* __restrict__ audio,
                                                     const float* __restrict__ text,
                                                     unsigned short* __restrict__ Ab,
                                                     unsigned short* __restrict__ Bb,
                                                     float* __restrict__ a2,
                                                     float* __restrict__ b2,
                                                     float* __restrict__ diag) {
    int wave = threadIdx.x >> 6;
    int lane = threadIdx.x & 63;
    int row  = blockIdx.x * 4 + wave;
    const float* ra = audio + (size_t)row * DDIM + lane * 8;
    const float* rt = text  + (size_t)row * DDIM + lane * 8;
    float4 a0 = *(const float4*)(ra), a1 = *(const float4*)(ra + 4);
    float4 t0 = *(const float4*)(rt), t1 = *(const float4*)(rt + 4);

    float sa = a0.x*a0.x + a0.y*a0.y + a0.z*a0.z + a0.w*a0.w
             + a1.x*a1.x + a1.y*a1.y + a1.z*a1.z + a1.w*a1.w;
    float st = t0.x*t0.x + t0.y*t0.y + t0.z*t0.z + t0.w*t0.w
             + t1.x*t1.x + t1.y*t1.y + t1.z*t1.z + t1.w*t1.w;
    float dt = a0.x*t0.x + a0.y*t0.y + a0.z*t0.z + a0.w*t0.w
             + a1.x*t1.x + a1.y*t1.y + a1.z*t1.z + a1.w*t1.w;

    unsigned short ua[8], ut[8];
    ua[0]=f2bf(a0.x); ua[1]=f2bf(a0.y); ua[2]=f2bf(a0.z); ua[3]=f2bf(a0.w);
    ua[4]=f2bf(a1.x); ua[5]=f2bf(a1.y); ua[6]=f2bf(a1.z); ua[7]=f2bf(a1.w);
    ut[0]=f2bf(t0.x); ut[1]=f2bf(t0.y); ut[2]=f2bf(t0.z); ut[3]=f2bf(t0.w);
    ut[4]=f2bf(t1.x); ut[5]=f2bf(t1.y); ut[6]=f2bf(t1.z); ut[7]=f2bf(t1.w);
    *(uint4*)(Ab + (size_t)row * DDIM + lane * 8) = *(const uint4*)ua;
    *(uint4*)(Bb + (size_t)row * DDIM + lane * 8) = *(const uint4*)ut;

    #pragma unroll
    for (int m = 1; m < 64; m <<= 1) {
        sa += __shfl_xor(sa, m);
        st += __shfl_xor(st, m);
        dt += __shfl_xor(dt, m);
    }
    if (lane == 0) {
        a2[row] = sa;
        b2[row] = st;
        float a2c  = fminf(sa, 1.0f - EPSF);
        float b2c  = fminf(st, 1.0f - EPSF);
        float diff = sa + st - 2.0f * dt;
        float den  = fmaxf((1.0f - a2c) * (1.0f - b2c), EPSF);
        float arg  = fmaxf(1.0f + 2.0f * diff / den, 1.0f + EPSF);
        diag[row]  = -logf(arg + sqrtf(arg * arg - 1.0f));
    }
}

// 256x256 MFMA GEMM (A@B^T) with fused hyperbolic-sim epilogue.
// 8 waves: wm = w>>2 (2 M-halves), wn = w&3 (4 N-quarters); wave out 128x64.
__global__ __launch_bounds__(512) void hyper_gemm(
    const unsigned short* __restrict__ A, const unsigned short* __restrict__ B,
    const float* __restrict__ a2, const float* __restrict__ b2,
    float* __restrict__ rowsum, float* __restrict__ colsum) {

    __shared__ char lds[2 * LDSBUF];   // [buf][A 32K | B 32K]

    const int tid  = threadIdx.x;
    const int lane = tid & 63;
    const int w    = tid >> 6;         // 0..7
    const int wm   = w >> 2;           // 0..1
    const int wn   = w & 3;            // 0..3

    // XCD-aware bijective swizzle (grid = 1024 = 32x32 tiles, 1024 % 8 == 0):
    // XCD x runs swz ids [128x, 128x+128) -> 4 consecutive tile-rows, A-panels hot.
    const int bid = blockIdx.x;
    const int swz = (bid & 7) * 128 + (bid >> 3);
    const int by  = swz >> 5;          // 0..31
    const int bx  = swz & 31;          // 0..31
    const int i0 = by * BM;
    const int j0 = bx * BN;

    const int g  = lane >> 4;          // 0..3
    const int cl = lane & 15;          // 0..15

    // ---- staging: wave w stages rows [32w,32w+32) of A and of B (4 chunks of
    // 8 rows each; 64 lanes x 16B = 1KB/chunk). Linear LDS dest; global col
    // pre-swizzled so the XOR-swizzled read pattern sees linear data (rule #21).
    const int srow = lane >> 3;                   // 0..7 within chunk
    const int scol = ((lane & 7) ^ srow) * 8;     // swizzled col (elements)
    const char* aP[4]; const char* bP[4]; int ldsOff[4];
    #pragma unroll
    for (int c = 0; c < 4; ++c) {
        int row = w * 32 + c * 8 + srow;
        aP[c] = (const char*)(A + (size_t)(i0 + row) * DDIM + scol);
        bP[c] = (const char*)(B + (size_t)(j0 + row) * DDIM + scol);
        ldsOff[c] = w * 4096 + c * 1024;
    }

    // ---- fragment ds_read byte offsets (rows: A 256x64, stride 128B; B +32768)
    int offA[8][2], offB[4][2];
    #pragma unroll
    for (int mi = 0; mi < 8; ++mi) {
        int rowA = wm * 128 + mi * 16 + cl;
        #pragma unroll
        for (int kh = 0; kh < 2; ++kh) {
            int cb = (kh * 32 + g * 8) * 2;
            offA[mi][kh] = rowA * 128 + (cb ^ ((rowA & 7) << 4));
        }
    }
    #pragma unroll
    for (int ni = 0; ni < 4; ++ni) {
        int rowB = wn * 64 + ni * 16 + cl;
        #pragma unroll
        for (int kh = 0; kh < 2; ++kh) {
            int cb = (kh * 32 + g * 8) * 2;
            offB[ni][kh] = 32768 + rowB * 128 + (cb ^ ((rowB & 7) << 4));
        }
    }

    f32x4 acc[8][4];
    #pragma unroll
    for (int mi = 0; mi < 8; ++mi)
        #pragma unroll
        for (int ni = 0; ni < 4; ++ni)
            acc[mi][ni] = (f32x4)0.0f;

#define STAGE(buf, t)                                                     \
    do {                                                                  \
        _Pragma("unroll")                                                 \
        for (int c = 0; c < 4; ++c) {                                     \
            GLOAD_LDS16(aP[c] + (t) * (BK * 2),                           \
                        lds + (buf) * LDSBUF + ldsOff[c]);                \
            GLOAD_LDS16(bP[c] + (t) * (BK * 2),                           \
                        lds + (buf) * LDSBUF + 32768 + ldsOff[c]);        \
        }                                                                 \
    } while (0)

#define COMPUTE(buf)                                                      \
    do {                                                                  \
        _Pragma("unroll")                                                 \
        for (int kh = 0; kh < 2; ++kh) {                                  \
            bf16x8 af[8], bv[4];                                          \
            _Pragma("unroll")                                             \
            for (int mi = 0; mi < 8; ++mi)                                \
                af[mi] = *(const bf16x8*)(lds + (buf) * LDSBUF + offA[mi][kh]); \
            _Pragma("unroll")                                             \
            for (int ni = 0; ni < 4; ++ni)                                \
                bv[ni] = *(const bf16x8*)(lds + (buf) * LDSBUF + offB[ni][kh]); \
            _Pragma("unroll")                                             \
            for (int mi = 0; mi < 8; ++mi)                                \
                _Pragma("unroll")                                         \
                for (int ni = 0; ni < 4; ++ni)                            \
                    acc[mi][ni] = __builtin_amdgcn_mfma_f32_16x16x32_bf16(\
                        af[mi], bv[ni], acc[mi][ni], 0, 0, 0);            \
        }                                                                 \
    } while (0)

    STAGE(0, 0);
    __syncthreads();                       // tile 0 resident
    #pragma unroll
    for (int t = 0; t < NT; ++t) {
        if (t + 1 < NT) STAGE((t + 1) & 1, t + 1);   // prefetch next tile
        COMPUTE(t & 1);
        if (t + 1 < NT) __syncthreads();   // drains prefetch + lds reads
    }
#undef STAGE
#undef COMPUTE

    // ---- epilogue: e = arg - sqrt(arg^2-1); accumulate row/col partials.
    float B2c[4], fb[4];
    #pragma unroll
    for (int ni = 0; ni < 4; ++ni) {
        float B2 = b2[j0 + wn * 64 + ni * 16 + cl];
        B2c[ni] = B2;
        fb[ni] = __builtin_amdgcn_rcpf(1.0f - fminf(B2, 1.0f - EPSF));
    }

    float cp[4] = {0.f, 0.f, 0.f, 0.f};
    #pragma unroll
    for (int mi = 0; mi < 8; ++mi) {
        #pragma unroll
        for (int reg = 0; reg < 4; ++reg) {
            int   gi  = i0 + wm * 128 + mi * 16 + g * 4 + reg;
            float A2  = a2[gi];
            float fa  = 2.0f * __builtin_amdgcn_rcpf(1.0f - fminf(A2, 1.0f - EPSF));
            float rsum = 0.f;
            #pragma unroll
            for (int ni = 0; ni < 4; ++ni) {
                float dot  = acc[mi][ni][reg];
                float diff = fmaf(-2.0f, dot, A2 + B2c[ni]);
                float arg  = fmaf(diff * fa, fb[ni], 1.0f);
                arg = fmaxf(arg, 1.0f);
                float sq = sqrtf(fmaf(arg, arg, -1.0f));
                float e  = arg - sq;      // exp(-arccosh(arg)), exact
                rsum += e;
                cp[ni] += e;
            }
            float v = rsum;
            v += __shfl_xor(v, 1); v += __shfl_xor(v, 2);
            v += __shfl_xor(v, 4); v += __shfl_xor(v, 8);
            if (cl == 0) atomicAdd(&rowsum[gi], v);
        }
    }
    #pragma unroll
    for (int ni = 0; ni < 4; ++ni) {
        float v = cp[ni];
        v += __shfl_xor(v, 16); v += __shfl_xor(v, 32);
        if (g == 0) atomicAdd(&colsum[j0 + wn * 64 + ni * 16 + cl], v);
    }
}

__global__ __launch_bounds__(256) void finalize(const float* __restrict__ rowsum,
                                                const float* __restrict__ colsum,
                                                const float* __restrict__ diag,
                                                float* __restrict__ out) {
    int i = blockIdx.x * 256 + threadIdx.x;
    float s = logf(rowsum[i]) + logf(colsum[i]) - 2.0f * diag[i];
    #pragma unroll
    for (int m = 1; m < 64; m <<= 1) s += __shfl_xor(s, m);
    if ((threadIdx.x & 63) == 0)
        atomicAdd(out, s * (1.0f / (2.0f * NROWS)));
}

extern "C" void kernel_launch(void* const* d_in, const int* in_sizes, int n_in,
                              void* d_out, int out_size, void* d_ws, size_t ws_size,
                              hipStream_t stream) {
    const float* audio = (const float*)d_in[0];
    const float* text  = (const float*)d_in[1];
    // labels (d_in[2]) are arange(N) -> diagonal; not needed.
    float* out = (float*)d_out;

    char* ws = (char*)d_ws;
    const size_t BF = (size_t)NROWS * DDIM * sizeof(unsigned short);  // 8 MiB
    unsigned short* Abf = (unsigned short*)ws;
    unsigned short* Bbf = (unsigned short*)(ws + BF);
    float* a2     = (float*)(ws + 2 * BF);
    float* b2     = a2 + NROWS;
    float* rowsum = b2 + NROWS;
    float* colsum = rowsum + NROWS;
    float* diag   = colsum + NROWS;

    hipMemsetAsync(rowsum, 0, 2 * NROWS * sizeof(float), stream);
    hipMemsetAsync(out, 0, sizeof(float), stream);
    convert_norms<<<NROWS / 4, 256, 0, stream>>>(audio, text, Abf, Bbf, a2, b2, diag);
    hyper_gemm<<<(NROWS / BM) * (NROWS / BN), 512, 0, stream>>>(Abf, Bbf, a2, b2, rowsum, colsum);
    finalize<<<NROWS / 256, 256, 0, stream>>>(rowsum, colsum, diag, out);
}

// Round 8
// 229.126 us; speedup vs baseline: 1.2109x; 1.2109x over previous
//
#include <hip/hip_runtime.h>
#include <hip/hip_bf16.h>

// HyperbolicContrastiveLoss: N=8192, D=512, f32 in, scalar f32 out.
// loss = (1/2N) * sum_i [ log(sum_j exp(sim_ij)) + log(sum_i exp(sim_ij)) - 2*sim_ii ]
// exp(sim) = exp(-arccosh(arg)) = arg - sqrt(arg^2-1)  (exact; (arg+s)(arg-s)=1)
// GEMM: 128x128 tile, BK=64, 8 waves (2M x 4N, wave-out 64x32), double-buffered
// global_load_lds (linear LDS dest + pre-swizzled global source + same XOR on
// reads). 2 blocks/CU x 8 waves = 16 waves/CU.

#define NROWS 8192
#define DDIM  512
#define BM 128
#define BN 128
#define BK 64
#define NT (DDIM / BK)   // 8 K-steps
#define LDSBUF 32768     // per-buffer bytes: A 16K | B 16K

typedef __attribute__((ext_vector_type(8))) short bf16x8;
typedef __attribute__((ext_vector_type(4))) float f32x4;

constexpr float EPSF = 1e-10f;

#define GLOAD_LDS16(g, l)                                                        \
    __builtin_amdgcn_global_load_lds(                                            \
        (const __attribute__((address_space(1))) void*)(g),                      \
        (__attribute__((address_space(3))) void*)(l), 16, 0, 0)

__device__ inline unsigned short f2bf(float f) {
    union { float f; unsigned int u; } x; x.f = f;
    unsigned int r = x.u + 0x7fffu + ((x.u >> 16) & 1u);  // RNE
    return (unsigned short)(r >> 16);
}

// One wave per row: convert audio+text row to bf16, row norms, and f32-precise
// diagonal sim_ii.
__global__ __launch_bounds__(256) void convert_norms(const float* __restrict__ audio,
                                                     const float* __restrict__ text,
                                                     unsigned short* __restrict__ Ab,
                                                     unsigned short* __restrict__ Bb,
                                                     float* __restrict__ a2,
                                                     float* __restrict__ b2,
                                                     float* __restrict__ diag) {
    int wave = threadIdx.x >> 6;
    int lane = threadIdx.x & 63;
    int row  = blockIdx.x * 4 + wave;
    const float* ra = audio + (size_t)row * DDIM + lane * 8;
    const float* rt = text  + (size_t)row * DDIM + lane * 8;
    float4 a0 = *(const float4*)(ra), a1 = *(const float4*)(ra + 4);
    float4 t0 = *(const float4*)(rt), t1 = *(const float4*)(rt + 4);

    float sa = a0.x*a0.x + a0.y*a0.y + a0.z*a0.z + a0.w*a0.w
             + a1.x*a1.x + a1.y*a1.y + a1.z*a1.z + a1.w*a1.w;
    float st = t0.x*t0.x + t0.y*t0.y + t0.z*t0.z + t0.w*t0.w
             + t1.x*t1.x + t1.y*t1.y + t1.z*t1.z + t1.w*t1.w;
    float dt = a0.x*t0.x + a0.y*t0.y + a0.z*t0.z + a0.w*t0.w
             + a1.x*t1.x + a1.y*t1.y + a1.z*t1.z + a1.w*t1.w;

    unsigned short ua[8], ut[8];
    ua[0]=f2bf(a0.x); ua[1]=f2bf(a0.y); ua[2]=f2bf(a0.z); ua[3]=f2bf(a0.w);
    ua[4]=f2bf(a1.x); ua[5]=f2bf(a1.y); ua[6]=f2bf(a1.z); ua[7]=f2bf(a1.w);
    ut[0]=f2bf(t0.x); ut[1]=f2bf(t0.y); ut[2]=f2bf(t0.z); ut[3]=f2bf(t0.w);
    ut[4]=f2bf(t1.x); ut[5]=f2bf(t1.y); ut[6]=f2bf(t1.z); ut[7]=f2bf(t1.w);
    *(uint4*)(Ab + (size_t)row * DDIM + lane * 8) = *(const uint4*)ua;
    *(uint4*)(Bb + (size_t)row * DDIM + lane * 8) = *(const uint4*)ut;

    #pragma unroll
    for (int m = 1; m < 64; m <<= 1) {
        sa += __shfl_xor(sa, m);
        st += __shfl_xor(st, m);
        dt += __shfl_xor(dt, m);
    }
    if (lane == 0) {
        a2[row] = sa;
        b2[row] = st;
        float a2c  = fminf(sa, 1.0f - EPSF);
        float b2c  = fminf(st, 1.0f - EPSF);
        float diff = sa + st - 2.0f * dt;
        float den  = fmaxf((1.0f - a2c) * (1.0f - b2c), EPSF);
        float arg  = fmaxf(1.0f + 2.0f * diff / den, 1.0f + EPSF);
        diag[row]  = -logf(arg + sqrtf(arg * arg - 1.0f));
    }
}

// 128x128 MFMA GEMM (A@B^T), 8 waves (wm=w>>2 in {0,1}, wn=w&3 in {0..3});
// wave output 64x32 = acc[4][2] frags. Fused hyperbolic-sim epilogue.
__global__ __launch_bounds__(512, 4) void hyper_gemm(
    const unsigned short* __restrict__ A, const unsigned short* __restrict__ B,
    const float* __restrict__ a2, const float* __restrict__ b2,
    float* __restrict__ rowsum, float* __restrict__ colsum) {

    __shared__ char lds[2 * LDSBUF];   // [buf][A 16K | B 16K]

    const int tid  = threadIdx.x;
    const int lane = tid & 63;
    const int w    = tid >> 6;         // 0..7
    const int wm   = w >> 2;           // 0..1
    const int wn   = w & 3;            // 0..3

    // XCD swizzle (round-5 proven, FETCH ~37MB): 8 consecutive dispatch slots on
    // one XCD share a B-panel (bx) with 8 different A-panels.
    const int bid = blockIdx.x;
    const int idx = bid >> 3;
    const int by  = (bid & 7) * 8 + (idx & 7);
    const int bx  = idx >> 3;
    const int i0 = by * BM;
    const int j0 = bx * BN;

    const int g  = lane >> 4;          // 0..3
    const int cl = lane & 15;          // 0..15

    // ---- staging: wave w stages rows [16w,16w+16) of A and B as 2 chunks of
    // 8 rows (64 lanes x 16B = 1KB/chunk). Linear LDS dest; global col
    // pre-swizzled so XOR-swizzled reads see linear data (rule #21).
    const int srow = lane >> 3;                   // 0..7 within chunk
    const int scol = ((lane & 7) ^ srow) * 8;     // swizzled col (elements)
    const char* aP[2]; const char* bP[2]; int ldsOff[2];
    #pragma unroll
    for (int c = 0; c < 2; ++c) {
        int row = w * 16 + c * 8 + srow;
        aP[c] = (const char*)(A + (size_t)(i0 + row) * DDIM + scol);
        bP[c] = (const char*)(B + (size_t)(j0 + row) * DDIM + scol);
        ldsOff[c] = w * 2048 + c * 1024;
    }

    // ---- fragment ds_read byte offsets (row stride 128B; B at +16384)
    int offA[4][2], offB[2][2];
    #pragma unroll
    for (int mi = 0; mi < 4; ++mi) {
        int rowA = wm * 64 + mi * 16 + cl;
        #pragma unroll
        for (int kh = 0; kh < 2; ++kh) {
            int cb = (kh * 32 + g * 8) * 2;
            offA[mi][kh] = rowA * 128 + (cb ^ ((rowA & 7) << 4));
        }
    }
    #pragma unroll
    for (int ni = 0; ni < 2; ++ni) {
        int rowB = wn * 32 + ni * 16 + cl;
        #pragma unroll
        for (int kh = 0; kh < 2; ++kh) {
            int cb = (kh * 32 + g * 8) * 2;
            offB[ni][kh] = 16384 + rowB * 128 + (cb ^ ((rowB & 7) << 4));
        }
    }

    f32x4 acc[4][2];
    #pragma unroll
    for (int mi = 0; mi < 4; ++mi)
        #pragma unroll
        for (int ni = 0; ni < 2; ++ni)
            acc[mi][ni] = (f32x4)0.0f;

#define STAGE(buf, t)                                                     \
    do {                                                                  \
        _Pragma("unroll")                                                 \
        for (int c = 0; c < 2; ++c) {                                     \
            GLOAD_LDS16(aP[c] + (t) * (BK * 2),                           \
                        lds + (buf) * LDSBUF + ldsOff[c]);                \
            GLOAD_LDS16(bP[c] + (t) * (BK * 2),                           \
                        lds + (buf) * LDSBUF + 16384 + ldsOff[c]);        \
        }                                                                 \
    } while (0)

#define COMPUTE(buf)                                                      \
    do {                                                                  \
        _Pragma("unroll")                                                 \
        for (int kh = 0; kh < 2; ++kh) {                                  \
            bf16x8 af[4], bv[2];                                          \
            _Pragma("unroll")                                             \
            for (int mi = 0; mi < 4; ++mi)                                \
                af[mi] = *(const bf16x8*)(lds + (buf) * LDSBUF + offA[mi][kh]); \
            _Pragma("unroll")                                             \
            for (int ni = 0; ni < 2; ++ni)                                \
                bv[ni] = *(const bf16x8*)(lds + (buf) * LDSBUF + offB[ni][kh]); \
            _Pragma("unroll")                                             \
            for (int mi = 0; mi < 4; ++mi)                                \
                _Pragma("unroll")                                         \
                for (int ni = 0; ni < 2; ++ni)                            \
                    acc[mi][ni] = __builtin_amdgcn_mfma_f32_16x16x32_bf16(\
                        af[mi], bv[ni], acc[mi][ni], 0, 0, 0);            \
        }                                                                 \
    } while (0)

    STAGE(0, 0);
    __syncthreads();                       // tile 0 resident
    #pragma unroll
    for (int t = 0; t < NT; ++t) {
        if (t + 1 < NT) STAGE((t + 1) & 1, t + 1);   // prefetch next tile
        COMPUTE(t & 1);
        if (t + 1 < NT) __syncthreads();   // drains prefetch + lds reads
    }
#undef STAGE
#undef COMPUTE

    // ---- epilogue: e = arg - sqrt(arg^2-1); accumulate row/col partials.
    float B2c[2], fb[2];
    #pragma unroll
    for (int ni = 0; ni < 2; ++ni) {
        float B2 = b2[j0 + wn * 32 + ni * 16 + cl];
        B2c[ni] = B2;
        fb[ni] = __builtin_amdgcn_rcpf(1.0f - fminf(B2, 1.0f - EPSF));
    }

    float cp[2] = {0.f, 0.f};
    #pragma unroll
    for (int mi = 0; mi < 4; ++mi) {
        #pragma unroll
        for (int reg = 0; reg < 4; ++reg) {
            int   gi  = i0 + wm * 64 + mi * 16 + g * 4 + reg;
            float A2  = a2[gi];
            float fa  = 2.0f * __builtin_amdgcn_rcpf(1.0f - fminf(A2, 1.0f - EPSF));
            float rsum = 0.f;
            #pragma unroll
            for (int ni = 0; ni < 2; ++ni) {
                float dot  = acc[mi][ni][reg];
                float diff = fmaf(-2.0f, dot, A2 + B2c[ni]);
                float arg  = fmaf(diff * fa, fb[ni], 1.0f);
                arg = fmaxf(arg, 1.0f);
                float sq = sqrtf(fmaf(arg, arg, -1.0f));
                float e  = arg - sq;      // exp(-arccosh(arg)), exact
                rsum += e;
                cp[ni] += e;
            }
            float v = rsum;
            v += __shfl_xor(v, 1); v += __shfl_xor(v, 2);
            v += __shfl_xor(v, 4); v += __shfl_xor(v, 8);
            if (cl == 0) atomicAdd(&rowsum[gi], v);
        }
    }
    #pragma unroll
    for (int ni = 0; ni < 2; ++ni) {
        float v = cp[ni];
        v += __shfl_xor(v, 16); v += __shfl_xor(v, 32);
        if (g == 0) atomicAdd(&colsum[j0 + wn * 32 + ni * 16 + cl], v);
    }
}

// Single block, direct write to out[0] (no memset, no atomics).
__global__ __launch_bounds__(1024) void finalize(const float* __restrict__ rowsum,
                                                 const float* __restrict__ colsum,
                                                 const float* __restrict__ diag,
                                                 float* __restrict__ out) {
    float s = 0.f;
    for (int i = threadIdx.x; i < NROWS; i += 1024)
        s += logf(rowsum[i]) + logf(colsum[i]) - 2.0f * diag[i];
    __shared__ float red[16];
    int lane = threadIdx.x & 63, wv = threadIdx.x >> 6;
    #pragma unroll
    for (int m = 1; m < 64; m <<= 1) s += __shfl_xor(s, m);
    if (lane == 0) red[wv] = s;
    __syncthreads();
    if (threadIdx.x == 0) {
        float t = 0.f;
        #pragma unroll
        for (int k = 0; k < 16; ++k) t += red[k];
        out[0] = t / (2.0f * NROWS);
    }
}

extern "C" void kernel_launch(void* const* d_in, const int* in_sizes, int n_in,
                              void* d_out, int out_size, void* d_ws, size_t ws_size,
                              hipStream_t stream) {
    const float* audio = (const float*)d_in[0];
    const float* text  = (const float*)d_in[1];
    // labels (d_in[2]) are arange(N) -> diagonal; not needed.
    float* out = (float*)d_out;

    char* ws = (char*)d_ws;
    const size_t BF = (size_t)NROWS * DDIM * sizeof(unsigned short);  // 8 MiB
    unsigned short* Abf = (unsigned short*)ws;
    unsigned short* Bbf = (unsigned short*)(ws + BF);
    float* a2     = (float*)(ws + 2 * BF);
    float* b2     = a2 + NROWS;
    float* rowsum = b2 + NROWS;
    float* colsum = rowsum + NROWS;
    float* diag   = colsum + NROWS;

    hipMemsetAsync(rowsum, 0, 2 * NROWS * sizeof(float), stream);
    convert_norms<<<NROWS / 4, 256, 0, stream>>>(audio, text, Abf, Bbf, a2, b2, diag);
    hyper_gemm<<<(NROWS / BM) * (NROWS / BN), 512, 0, stream>>>(Abf, Bbf, a2, b2, rowsum, colsum);
    finalize<<<1, 1024, 0, stream>>>(rowsum, colsum, diag, out);
}